// Round 5
// baseline (396.356 us; speedup 1.0000x reference)
//
#include <hip/hip_runtime.h>

typedef __bf16 bf16_t;
typedef __bf16 bf16x4_t __attribute__((ext_vector_type(4)));
typedef __bf16 bf16x8_t __attribute__((ext_vector_type(8)));
typedef float f32x16_t __attribute__((ext_vector_type(16)));

// ---------------------------------------------------------------------------
// Repack weight (oc, ic, ky, kx) fp32 -> bf16
//   layout: [half(2)][kc(8)][tap(9)][hw(2)][ocl(64)][icl(8)]
//   oc = half*64+ocl, ic = kc*16 + hw*8 + icl, tap = ky*3+kx
// Matches conv's LDS-resident B exactly (stage = linear memcpy).
// ---------------------------------------------------------------------------
__global__ __launch_bounds__(256) void repack_kernel(const float* __restrict__ w,
                                                     bf16_t* __restrict__ wt) {
  int flat = blockIdx.x * 256 + threadIdx.x;  // 2*8*9*2*64*8 = 147456 exact
  int half = flat / 73728;
  int r = flat % 73728;
  int icl = r & 7;
  int r2 = r >> 3;
  int ocl = r2 & 63;
  int r3 = r2 >> 6;
  int hw = r3 & 1;
  int r4 = r3 >> 1;
  int tap = r4 % 9;
  int kc = r4 / 9;
  int oc = half * 64 + ocl;
  int ic = kc * 16 + hw * 8 + icl;
  wt[flat] = (bf16_t)w[((size_t)oc * 128 + ic) * 9 + tap];
}

// ---------------------------------------------------------------------------
// Zero the pad ring/slack of a padded NHWC bf16 array (Hp x Wp, 128 ch).
// Interior = rows 1..h, cols 1..w. One thread per (b, pixel); border threads
// write 256 B of zeros, interior threads exit.
// ---------------------------------------------------------------------------
__global__ __launch_bounds__(256) void border_kernel(char* __restrict__ subp,
                                                     int h, int w, int Hp, int Wp) {
  int flat = blockIdx.x * 256 + threadIdx.x;
  int per_img = Hp * Wp;
  if (flat >= 8 * per_img) return;
  int p = flat % per_img;
  int row = p / Wp;
  int col = p - row * Wp;
  if (row >= 1 && row <= h && col >= 1 && col <= w) return;
  uint4* dst = (uint4*)(subp + (size_t)flat * 256);
  uint4 z = make_uint4(0u, 0u, 0u, 0u);
#pragma unroll
  for (int i = 0; i < 16; ++i) dst[i] = z;
}

// ---------------------------------------------------------------------------
// DWT: in fp32 (B,32,2h,2w) -> sub bf16 padded NHWC (B,Hp,Wp,128) at +1 offset,
// ci=4c+q; ll fp32 (B,32,h,w). 256 thr = 64 j-lanes x 4 c-groups.
// ---------------------------------------------------------------------------
__global__ __launch_bounds__(256) void dwt_kernel(const float* __restrict__ in,
                                                  bf16_t* __restrict__ sub,
                                                  float* __restrict__ llout,
                                                  int h, int w, int Hp, int Wp) {
  __shared__ __align__(16) bf16_t lds[64 * 132];
  const int bi = blockIdx.z;
  const int i = blockIdx.y;
  const int j0 = blockIdx.x * 64;
  const int tid = threadIdx.x;
  const int j = tid & 63;
  const int cg = tid >> 6;
  const int jg = j0 + j;
  const bool jok = jg < w;
  const int H2 = h * 2, W2 = w * 2;
  for (int c = cg; c < 32; c += 4) {
    float va = 0.f, vb = 0.f, vc = 0.f, vd = 0.f;
    if (jok) {
      const float2* p0 = (const float2*)(in + ((size_t)(bi * 32 + c) * H2 + 2 * i) * W2);
      const float2* p1 = (const float2*)(in + ((size_t)(bi * 32 + c) * H2 + 2 * i + 1) * W2);
      float2 r0 = p0[jg];
      float2 r1 = p1[jg];
      va = r0.x; vb = r0.y; vc = r1.x; vd = r1.y;
    }
    float ll = (va + vb + vc + vd) * 0.5f;
    float lh = (va - vb + vc - vd) * 0.5f;
    float hl = (va + vb - vc - vd) * 0.5f;
    float hh = (va - vb - vc + vd) * 0.5f;
    bf16x4_t q;
    q.x = (bf16_t)ll; q.y = (bf16_t)lh; q.z = (bf16_t)hl; q.w = (bf16_t)hh;
    *(bf16x4_t*)(&lds[j * 132 + c * 4]) = q;
    if (llout != nullptr && jok)
      llout[((size_t)(bi * 32 + c) * h + i) * w + jg] = ll;
  }
  __syncthreads();
  // padded store base: interior starts at (+1,+1)
  const size_t obase = ((size_t)bi * Hp + (i + 1)) * Wp + (j0 + 1);
  for (int it = 0; it < 8; ++it) {
    int flat = it * 256 + tid;  // 2048 slots of 4 bf16
    int jj = flat >> 5;
    int c4 = flat & 31;
    if (j0 + jj < w) {
      bf16x4_t q = *(const bf16x4_t*)(&lds[jj * 132 + c4 * 4]);
      *(bf16x4_t*)(sub + ((obase + jj) << 7) + c4 * 4) = q;
    }
  }
}

// ---------------------------------------------------------------------------
// Conv 3x3 pad1, 128ic -> 64oc (one half per blockIdx.y), MFMA 32x32x16 bf16.
// All 9-tap weights for the half resident in LDS (147456 B, 1 block/CU).
// ZERO barriers in the K-loop: A read directly from zero-padded global NHWC.
// kc (16-ic slab) OUTER, tap INNER -> 9-tap sweep hits an L1-sized slab.
// Block = 4 waves; wave w owns rows 4w..4w+3 of a 16x16 tile; acc[2][2]
// (mt: 2-row pairs, nt: oc halves 0/32). Blocks loop over tiles, staging once.
// ---------------------------------------------------------------------------
__global__ __launch_bounds__(256, 1) void conv_kernel(const char* __restrict__ subp,
                                                      const uint4* __restrict__ wt4,
                                                      float* __restrict__ y,
                                                      int h, int w, int Hp, int Wp,
                                                      int tilesX, int tilesPerImg,
                                                      int nTiles) {
  __shared__ uint4 Bs[9216];               // 147456 B
  const int tid = threadIdx.x;
  const int half = blockIdx.y;

  // ---- stage all weights for this oc-half: linear 147456-byte copy ----
  const uint4* src = wt4 + (size_t)half * 9216;
#pragma unroll
  for (int i = 0; i < 36; ++i) Bs[i * 256 + tid] = src[i * 256 + tid];
  __syncthreads();

  const int lane = tid & 63;
  const int wav = tid >> 6;                // wave -> rows 4w..4w+3
  const int m = lane & 31;                 // pixel index in 32-tile
  const int hw_ = lane >> 5;               // k-half (8-ic)
  const int r_l = m >> 4;                  // 0..1
  const int c_l = m & 15;                  // 0..15
  const int nl = lane & 31;                // oc lane within 32
  const char* BsB = (const char*)Bs;

  for (int t = blockIdx.x; t < nTiles; t += gridDim.x) {
    const int b = t / tilesPerImg;
    const int rem = t - b * tilesPerImg;
    const int ty = rem / tilesX;
    const int tx = rem - ty * tilesX;

    // per-mt A byte-base at tap(ky=0,kx=0): pad(+1) and (ky-1) cancel
    size_t pixbase0, pixbase1;
    {
      const int colg = tx * 16 + c_l;
      const int row0 = ty * 16 + wav * 4 + 0 * 2 + r_l;
      const int row1 = ty * 16 + wav * 4 + 1 * 2 + r_l;
      pixbase0 = (((size_t)b * Hp + row0) * Wp + colg) * 256 + hw_ * 16;
      pixbase1 = (((size_t)b * Hp + row1) * Wp + colg) * 256 + hw_ * 16;
    }

    f32x16_t acc00 = {}, acc01 = {}, acc10 = {}, acc11 = {};

    for (int kc = 0; kc < 8; ++kc) {
      const int kcoff = kc * 32;
#pragma unroll
      for (int tap = 0; tap < 9; ++tap) {
        const int ky = tap / 3;
        const int kx = tap - ky * 3;
        const size_t off = ((size_t)ky * Wp + kx) * 256 + kcoff;
        bf16x8_t a0 = *(const bf16x8_t*)(subp + pixbase0 + off);
        bf16x8_t a1 = *(const bf16x8_t*)(subp + pixbase1 + off);
        const char* bb = BsB + (((size_t)((kc * 9 + tap) * 2 + hw_)) * 64 + nl) * 16;
        bf16x8_t b0 = *(const bf16x8_t*)(bb);
        bf16x8_t b1 = *(const bf16x8_t*)(bb + 512);
        acc00 = __builtin_amdgcn_mfma_f32_32x32x16_bf16(a0, b0, acc00, 0, 0, 0);
        acc01 = __builtin_amdgcn_mfma_f32_32x32x16_bf16(a0, b1, acc01, 0, 0, 0);
        acc10 = __builtin_amdgcn_mfma_f32_32x32x16_bf16(a1, b0, acc10, 0, 0, 0);
        acc11 = __builtin_amdgcn_mfma_f32_32x32x16_bf16(a1, b1, acc11, 0, 0, 0);
      }
    }

    // epilogue: D row=(reg&3)+8*(reg>>2)+4*hw_, col=lane&31 (verified layout)
#pragma unroll
    for (int reg = 0; reg < 16; ++reg) {
      const int row = (reg & 3) + ((reg >> 2) << 3) + (hw_ << 2);  // 0..31
      const int rr = row >> 4;
      const int cc = row & 15;
      {
        const int gy = ty * 16 + wav * 4 + 0 * 2 + rr;
        const int gx = tx * 16 + cc;
        if (gy < h && gx < w) {
          float* yp = y + (((size_t)b * h + gy) * w + gx) * 128 + half * 64 + nl;
          yp[0] = acc00[reg];
          yp[32] = acc01[reg];
        }
      }
      {
        const int gy = ty * 16 + wav * 4 + 1 * 2 + rr;
        const int gx = tx * 16 + cc;
        if (gy < h && gx < w) {
          float* yp = y + (((size_t)b * h + gy) * w + gx) * 128 + half * 64 + nl;
          yp[0] = acc10[reg];
          yp[32] = acc11[reg];
        }
      }
    }
    // no barrier between tiles: Bs is read-only after the one-time stage
  }
}

// ---------------------------------------------------------------------------
// IDWT: y fp32 NHWC (B,h,w,128) [+ nll fp32 (B,32,h,w)] [+ bias] -> out fp32 (B,32,2h,2w)
// ---------------------------------------------------------------------------
__global__ __launch_bounds__(256) void idwt_kernel(const float* __restrict__ y,
                                                   const float* __restrict__ nll,
                                                   const float* __restrict__ bias,
                                                   float* __restrict__ out,
                                                   int h, int w) {
  __shared__ __align__(16) float lds[32 * 132];
  const int bi = blockIdx.z;
  const int i = blockIdx.y;
  const int j0 = blockIdx.x * 32;
  const int tid = threadIdx.x;
  const size_t ybase = ((size_t)bi * h + i) * w;
  for (int it = 0; it < 4; ++it) {
    int flat = it * 256 + tid;  // 1024 float4 slots
    int jj = flat >> 5;
    int c4 = flat & 31;
    if (j0 + jj < w) {
      float4 v = *(const float4*)(y + ((ybase + j0 + jj) << 7) + c4 * 4);
      *(float4*)(&lds[jj * 132 + c4 * 4]) = v;
    }
  }
  __syncthreads();
  const int j = tid & 31;
  const int c0 = tid >> 5;
  const int jg = j0 + j;
  if (jg >= w) return;
  const int W2 = w * 2;
  for (int c = c0; c < 32; c += 8) {
    float4 s = *(const float4*)(&lds[j * 132 + c * 4]);
    float ll = s.x, lh = s.y, hl = s.z, hh = s.w;
    if (nll != nullptr) ll += nll[((size_t)(bi * 32 + c) * h + i) * w + jg];
    float a = (ll + lh + hl + hh) * 0.5f;
    float b2 = (ll - lh + hl - hh) * 0.5f;
    float c2 = (ll + lh - hl - hh) * 0.5f;
    float d2 = (ll - lh - hl + hh) * 0.5f;
    if (bias != nullptr) {
      float bv = bias[c];
      a += bv; b2 += bv; c2 += bv; d2 += bv;
    }
    float* o0 = out + ((size_t)(bi * 32 + c) * (2 * h) + 2 * i) * W2 + 2 * jg;
    *(float2*)o0 = make_float2(a, b2);
    *(float2*)(o0 + W2) = make_float2(c2, d2);
  }
}

// ---------------------------------------------------------------------------
// Workspace layout (bytes, peak 91,136,000). SIZES RE-DERIVED (r4 bug: nll2 is
// (8,32,56,56)=3,211,264 B and nll1 is (8,32,112,112)=12,845,056 B — the
// UPSAMPLED dims; round 4 under-sized both and idwt1 clobbered y1).
//   wt     @ 0          (294,912)
//   sub0p  @ 294,912    (26,615,808 = 8*114*114*256) -> ends 26,910,720  [dead after conv0]
//     reuse: sub1p @ 294,912   (8,921,088 = 8*66*66*256) -> 9,216,000
//            ll1   @ 9,216,000 (3,211,264) -> 12,427,264
//            sub2p @ 12,427,264 (2,367,488 = 8*34*34*256) -> 14,794,752
//            y2    @ 14,794,752 (3,211,264) -> 18,006,016
//            nll2  @ 18,006,016 (3,211,264) -> 21,217,280
//            nll1  @ 294,912   (12,845,056) -> 13,139,968  [written by idwt1,
//              when sub0p/sub1p/ll1/sub2p are all dead; disjoint from nll2/y1/y0]
//   ll0    @ 26,910,720 (12,845,056) -> 39,755,776  [dead after dwt1] -> y1 reuse
//   y0     @ 39,755,776 (51,380,224) -> 91,136,000
// ---------------------------------------------------------------------------
extern "C" void kernel_launch(void* const* d_in, const int* in_sizes, int n_in,
                              void* d_out, int out_size, void* d_ws, size_t ws_size,
                              hipStream_t stream) {
  if (ws_size < 91136000u) return;  // defensive: avoid OOB ws writes

  const float* x = (const float*)d_in[0];
  const float* weight = (const float*)d_in[1];
  const float* bias = (const float*)d_in[2];
  float* out = (float*)d_out;
  char* ws = (char*)d_ws;

  bf16_t* wt = (bf16_t*)(ws);
  char* sub0p = ws + 294912;
  char* sub1p = ws + 294912;
  float* ll1 = (float*)(ws + 9216000);
  char* sub2p = ws + 12427264;
  float* y2 = (float*)(ws + 14794752);
  float* nll2 = (float*)(ws + 18006016);
  float* nll1 = (float*)(ws + 294912);   // reuses dead sub0p/sub1p/ll1/sub2p space
  float* ll0 = (float*)(ws + 26910720);
  float* y1 = (float*)(ws + 26910720);
  float* y0 = (float*)(ws + 39755776);

  repack_kernel<<<576, 256, 0, stream>>>(weight, wt);

  // level 0: 112x112, padded 114x114, tiles 7x7
  border_kernel<<<407, 256, 0, stream>>>(sub0p, 112, 112, 114, 114);
  dwt_kernel<<<dim3(2, 112, 8), 256, 0, stream>>>(x, (bf16_t*)sub0p, ll0, 112, 112, 114, 114);
  conv_kernel<<<dim3(128, 2), 256, 0, stream>>>(sub0p, (const uint4*)wt, y0,
                                                112, 112, 114, 114, 7, 49, 392);
  // level 1: 56x56, padded 66x66 (tiles 4x4 of 16 cover 64)
  border_kernel<<<137, 256, 0, stream>>>(sub1p, 56, 56, 66, 66);
  dwt_kernel<<<dim3(1, 56, 8), 256, 0, stream>>>(ll0, (bf16_t*)sub1p, ll1, 56, 56, 66, 66);
  conv_kernel<<<dim3(128, 2), 256, 0, stream>>>(sub1p, (const uint4*)wt, y1,
                                                56, 56, 66, 66, 4, 16, 128);
  // level 2: 28x28, padded 34x34 (tiles 2x2 of 16 cover 32)
  border_kernel<<<37, 256, 0, stream>>>(sub2p, 28, 28, 34, 34);
  dwt_kernel<<<dim3(1, 28, 8), 256, 0, stream>>>(ll1, (bf16_t*)sub2p, nullptr, 28, 28, 34, 34);
  conv_kernel<<<dim3(32, 2), 256, 0, stream>>>(sub2p, (const uint4*)wt, y2,
                                               28, 28, 34, 34, 2, 4, 32);
  // inverse chain (nll2/nll1 are the UPSAMPLED outputs: 56x56 and 112x112)
  idwt_kernel<<<dim3(1, 28, 8), 256, 0, stream>>>(y2, nullptr, nullptr, nll2, 28, 28);
  idwt_kernel<<<dim3(2, 56, 8), 256, 0, stream>>>(y1, nll2, nullptr, nll1, 56, 56);
  idwt_kernel<<<dim3(4, 112, 8), 256, 0, stream>>>(y0, nll1, bias, out, 112, 112);
}

// Round 6
// 340.304 us; speedup vs baseline: 1.1647x; 1.1647x over previous
//
#include <hip/hip_runtime.h>

typedef __bf16 bf16_t;
typedef __bf16 bf16x4_t __attribute__((ext_vector_type(4)));
typedef __bf16 bf16x8_t __attribute__((ext_vector_type(8)));
typedef float f32x16_t __attribute__((ext_vector_type(16)));

// ---------------------------------------------------------------------------
// Repack weight (oc, ic, ky, kx) fp32 -> bf16
//   layout: [kc(8)][tap(9)][hw(2)][oc(128)][icl(8)]   (36864 B per kc-slab)
//   ic = kc*16 + hw*8 + icl, tap = ky*3+kx
// conv stages one kc-slab at a time as a linear 36864-byte memcpy.
// ---------------------------------------------------------------------------
__global__ __launch_bounds__(256) void repack_kernel(const float* __restrict__ w,
                                                     bf16_t* __restrict__ wt) {
  int flat = blockIdx.x * 256 + threadIdx.x;  // 8*9*2*128*8 = 147456 exact
  int icl = flat & 7;
  int oc = (flat >> 3) & 127;
  int g = flat >> 10;          // kc*18 + tap*2 + hw
  int kc = g / 18;
  int r = g - kc * 18;
  int tap = r >> 1;
  int hw = r & 1;
  int ic = kc * 16 + hw * 8 + icl;
  wt[flat] = (bf16_t)w[((size_t)oc * 128 + ic) * 9 + tap];
}

// ---------------------------------------------------------------------------
// Zero the pad ring/slack of a padded NHWC bf16 array (Hp x Wp, 128 ch).
// ---------------------------------------------------------------------------
__global__ __launch_bounds__(256) void border_kernel(char* __restrict__ subp,
                                                     int h, int w, int Hp, int Wp) {
  int flat = blockIdx.x * 256 + threadIdx.x;
  int per_img = Hp * Wp;
  if (flat >= 8 * per_img) return;
  int p = flat % per_img;
  int row = p / Wp;
  int col = p - row * Wp;
  if (row >= 1 && row <= h && col >= 1 && col <= w) return;
  uint4* dst = (uint4*)(subp + (size_t)flat * 256);
  uint4 z = make_uint4(0u, 0u, 0u, 0u);
#pragma unroll
  for (int i = 0; i < 16; ++i) dst[i] = z;
}

// ---------------------------------------------------------------------------
// DWT: in fp32 (B,32,2h,2w) -> sub bf16 padded NHWC (B,Hp,Wp,128) at +1 offset,
// ci=4c+q; ll fp32 (B,32,h,w). 256 thr = 64 j-lanes x 4 c-groups.
// ---------------------------------------------------------------------------
__global__ __launch_bounds__(256) void dwt_kernel(const float* __restrict__ in,
                                                  bf16_t* __restrict__ sub,
                                                  float* __restrict__ llout,
                                                  int h, int w, int Hp, int Wp) {
  __shared__ __align__(16) bf16_t lds[64 * 132];
  const int bi = blockIdx.z;
  const int i = blockIdx.y;
  const int j0 = blockIdx.x * 64;
  const int tid = threadIdx.x;
  const int j = tid & 63;
  const int cg = tid >> 6;
  const int jg = j0 + j;
  const bool jok = jg < w;
  const int H2 = h * 2, W2 = w * 2;
  for (int c = cg; c < 32; c += 4) {
    float va = 0.f, vb = 0.f, vc = 0.f, vd = 0.f;
    if (jok) {
      const float2* p0 = (const float2*)(in + ((size_t)(bi * 32 + c) * H2 + 2 * i) * W2);
      const float2* p1 = (const float2*)(in + ((size_t)(bi * 32 + c) * H2 + 2 * i + 1) * W2);
      float2 r0 = p0[jg];
      float2 r1 = p1[jg];
      va = r0.x; vb = r0.y; vc = r1.x; vd = r1.y;
    }
    float ll = (va + vb + vc + vd) * 0.5f;
    float lh = (va - vb + vc - vd) * 0.5f;
    float hl = (va + vb - vc - vd) * 0.5f;
    float hh = (va - vb - vc + vd) * 0.5f;
    bf16x4_t q;
    q.x = (bf16_t)ll; q.y = (bf16_t)lh; q.z = (bf16_t)hl; q.w = (bf16_t)hh;
    *(bf16x4_t*)(&lds[j * 132 + c * 4]) = q;
    if (llout != nullptr && jok)
      llout[((size_t)(bi * 32 + c) * h + i) * w + jg] = ll;
  }
  __syncthreads();
  const size_t obase = ((size_t)bi * Hp + (i + 1)) * Wp + (j0 + 1);
  for (int it = 0; it < 8; ++it) {
    int flat = it * 256 + tid;
    int jj = flat >> 5;
    int c4 = flat & 31;
    if (j0 + jj < w) {
      bf16x4_t q = *(const bf16x4_t*)(&lds[jj * 132 + c4 * 4]);
      *(bf16x4_t*)(sub + ((obase + jj) << 7) + c4 * 4) = q;
    }
  }
}

// ---------------------------------------------------------------------------
// Conv 3x3 pad1, 128ic -> 128oc, MFMA 32x32x16 bf16.
// Block: 512 thr (8 waves), M=256 (16x16 px tile), N=128.
// Wave grid 4x2: wave (wr,wc) -> rows wr*4..+3, oc base wc*64; wave-tile 64x64
// = acc 2x2 f32x16 -> 1 ds_read_b128 per MFMA (LDS-BW optimal ratio).
// LDS: A-halo 18x18 px x 256 B = 82944 (staged once/tile, chunk-XOR swizzle)
//    + B double-buffer 2 x 36864 (one 16-ic slab, all 128 oc, all 9 taps)
//    = 156672 B -> 1 block/CU, 8 waves. One barrier per kc (9 per tile),
//    each covering 288 block-MFMAs; B[kc+1] prefetched from L2-hot wt.
// ---------------------------------------------------------------------------
__global__ __launch_bounds__(512, 2) void conv_kernel(const char* __restrict__ subp,
                                                      const char* __restrict__ wt,
                                                      float* __restrict__ y,
                                                      int h, int w, int Hp, int Wp,
                                                      int tilesX, int tilesPerImg,
                                                      int nTiles) {
  __shared__ __align__(16) char lds[156672];
  char* As = lds;                 // 82944 B
  char* Bb = lds + 82944;         // 2 x 36864 B
  const int tid = threadIdx.x;
  const int lane = tid & 63;
  const int wav = tid >> 6;
  const int wr = wav >> 1;        // 0..3
  const int wc = wav & 1;         // 0..1
  const int m = lane & 31;
  const int hw_ = lane >> 5;
  const int r_l = m >> 4;
  const int c_l = m & 15;

  for (int t = blockIdx.x; t < nTiles; t += gridDim.x) {
    const int b = t / tilesPerImg;
    const int rem = t - b * tilesPerImg;
    const int ty = rem / tilesX;
    const int tx = rem - ty * tilesX;

    // ---- stage A halo: 324 px x 16 chunks of 16 B, swizzled slot = ch^(p&7)
    {
      const char* base = subp + (((size_t)b * Hp + ty * 16) * Wp + tx * 16) * 256;
      for (int it = 0; it < 11; ++it) {
        int cid = it * 512 + tid;          // 5184 = 81 waves' worth (wave-aligned)
        if (cid < 5184) {
          int p = cid >> 4;
          int ch = cid & 15;
          int r = p / 18;
          int c = p - r * 18;
          uint4 v = *(const uint4*)(base + ((size_t)r * Wp + c) * 256 + ch * 16);
          *(uint4*)(As + p * 256 + ((ch ^ (p & 7)) << 4)) = v;
        }
      }
    }
    // ---- stage B slab kc=0 (linear copy) ----
    for (int it = 0; it < 5; ++it) {
      int cid = it * 512 + tid;            // 2304 chunks (wave-aligned)
      if (cid < 2304) *(uint4*)(Bb + cid * 16) = *(const uint4*)(wt + cid * 16);
    }
    __syncthreads();

    f32x16_t acc00 = {}, acc01 = {}, acc10 = {}, acc11 = {};

    for (int kc = 0; kc < 8; ++kc) {
      const char* cur = Bb + (kc & 1) * 36864;
      if (kc < 7) {                         // prefetch next slab into other buf
        const char* src = wt + (size_t)(kc + 1) * 36864;
        char* dst = Bb + ((kc + 1) & 1) * 36864;
        for (int it = 0; it < 5; ++it) {
          int cid = it * 512 + tid;
          if (cid < 2304) *(uint4*)(dst + cid * 16) = *(const uint4*)(src + cid * 16);
        }
      }
      const int ch = kc * 2 + hw_;
#pragma unroll
      for (int tap = 0; tap < 9; ++tap) {
        const int ky = tap / 3;
        const int kx = tap - ky * 3;
        const int p0 = (wr * 4 + r_l + ky) * 18 + (c_l + kx);   // mt=0
        const int p1 = p0 + 36;                                 // mt=1 (+2 rows)
        bf16x8_t a0 = *(const bf16x8_t*)(As + p0 * 256 + ((ch ^ (p0 & 7)) << 4));
        bf16x8_t a1 = *(const bf16x8_t*)(As + p1 * 256 + ((ch ^ (p1 & 7)) << 4));
        const char* bb = cur + (((tap * 2 + hw_) * 128 + wc * 64 + m) << 4);
        bf16x8_t b0 = *(const bf16x8_t*)(bb);
        bf16x8_t b1 = *(const bf16x8_t*)(bb + 512);             // +32 oc
        acc00 = __builtin_amdgcn_mfma_f32_32x32x16_bf16(a0, b0, acc00, 0, 0, 0);
        acc01 = __builtin_amdgcn_mfma_f32_32x32x16_bf16(a0, b1, acc01, 0, 0, 0);
        acc10 = __builtin_amdgcn_mfma_f32_32x32x16_bf16(a1, b0, acc10, 0, 0, 0);
        acc11 = __builtin_amdgcn_mfma_f32_32x32x16_bf16(a1, b1, acc11, 0, 0, 0);
      }
      __syncthreads();   // B[kc+1] staged + all reads of cur done
    }

    // epilogue: D row=(reg&3)+8*(reg>>2)+4*hw_, col=lane&31 (verified layout)
    const int ocl = wc * 64 + m;
#pragma unroll
    for (int reg = 0; reg < 16; ++reg) {
      const int row = (reg & 3) + ((reg >> 2) << 3) + (hw_ << 2);
      const int rr = row >> 4;
      const int cc = row & 15;
      const int gx = tx * 16 + cc;
      {
        const int gy = ty * 16 + wr * 4 + rr;          // mt=0
        if (gy < h && gx < w) {
          float* yp = y + (((size_t)b * h + gy) * w + gx) * 128 + ocl;
          yp[0] = acc00[reg];
          yp[32] = acc01[reg];
        }
      }
      {
        const int gy = ty * 16 + wr * 4 + 2 + rr;      // mt=1
        if (gy < h && gx < w) {
          float* yp = y + (((size_t)b * h + gy) * w + gx) * 128 + ocl;
          yp[0] = acc10[reg];
          yp[32] = acc11[reg];
        }
      }
    }
  }
}

// ---------------------------------------------------------------------------
// IDWT: y fp32 NHWC (B,h,w,128) [+ nll fp32 (B,32,h,w)] [+ bias] -> out fp32 (B,32,2h,2w)
// ---------------------------------------------------------------------------
__global__ __launch_bounds__(256) void idwt_kernel(const float* __restrict__ y,
                                                   const float* __restrict__ nll,
                                                   const float* __restrict__ bias,
                                                   float* __restrict__ out,
                                                   int h, int w) {
  __shared__ __align__(16) float lds[32 * 132];
  const int bi = blockIdx.z;
  const int i = blockIdx.y;
  const int j0 = blockIdx.x * 32;
  const int tid = threadIdx.x;
  const size_t ybase = ((size_t)bi * h + i) * w;
  for (int it = 0; it < 4; ++it) {
    int flat = it * 256 + tid;
    int jj = flat >> 5;
    int c4 = flat & 31;
    if (j0 + jj < w) {
      float4 v = *(const float4*)(y + ((ybase + j0 + jj) << 7) + c4 * 4);
      *(float4*)(&lds[jj * 132 + c4 * 4]) = v;
    }
  }
  __syncthreads();
  const int j = tid & 31;
  const int c0 = tid >> 5;
  const int jg = j0 + j;
  if (jg >= w) return;
  const int W2 = w * 2;
  for (int c = c0; c < 32; c += 8) {
    float4 s = *(const float4*)(&lds[j * 132 + c * 4]);
    float ll = s.x, lh = s.y, hl = s.z, hh = s.w;
    if (nll != nullptr) ll += nll[((size_t)(bi * 32 + c) * h + i) * w + jg];
    float a = (ll + lh + hl + hh) * 0.5f;
    float b2 = (ll - lh + hl - hh) * 0.5f;
    float c2 = (ll + lh - hl - hh) * 0.5f;
    float d2 = (ll - lh - hl + hh) * 0.5f;
    if (bias != nullptr) {
      float bv = bias[c];
      a += bv; b2 += bv; c2 += bv; d2 += bv;
    }
    float* o0 = out + ((size_t)(bi * 32 + c) * (2 * h) + 2 * i) * W2 + 2 * jg;
    *(float2*)o0 = make_float2(a, b2);
    *(float2*)(o0 + W2) = make_float2(c2, d2);
  }
}

// ---------------------------------------------------------------------------
// Workspace layout (bytes, peak 91,136,000) — identical to round 5 (verified):
//   wt     @ 0          (294,912)
//   sub0p  @ 294,912    (26,615,808) [dead after conv0]
//     reuse: sub1p @ 294,912 (8,921,088); ll1 @ 9,216,000 (3,211,264);
//            sub2p @ 12,427,264 (2,367,488); y2 @ 14,794,752 (3,211,264);
//            nll2 @ 18,006,016 (3,211,264); nll1 @ 294,912 (12,845,056,
//              written by idwt1 when sub*/ll1 are dead; disjoint from nll2/y1/y0)
//   ll0    @ 26,910,720 (12,845,056) [dead after dwt1] -> y1 reuse
//   y0     @ 39,755,776 (51,380,224) -> 91,136,000
// ---------------------------------------------------------------------------
extern "C" void kernel_launch(void* const* d_in, const int* in_sizes, int n_in,
                              void* d_out, int out_size, void* d_ws, size_t ws_size,
                              hipStream_t stream) {
  if (ws_size < 91136000u) return;  // defensive: avoid OOB ws writes

  const float* x = (const float*)d_in[0];
  const float* weight = (const float*)d_in[1];
  const float* bias = (const float*)d_in[2];
  float* out = (float*)d_out;
  char* ws = (char*)d_ws;

  char* wt = ws;
  char* sub0p = ws + 294912;
  char* sub1p = ws + 294912;
  float* ll1 = (float*)(ws + 9216000);
  char* sub2p = ws + 12427264;
  float* y2 = (float*)(ws + 14794752);
  float* nll2 = (float*)(ws + 18006016);
  float* nll1 = (float*)(ws + 294912);
  float* ll0 = (float*)(ws + 26910720);
  float* y1 = (float*)(ws + 26910720);
  float* y0 = (float*)(ws + 39755776);

  repack_kernel<<<576, 256, 0, stream>>>(weight, (bf16_t*)wt);

  // level 0: 112x112, padded 114x114, tiles 7x7 of 16
  border_kernel<<<407, 256, 0, stream>>>(sub0p, 112, 112, 114, 114);
  dwt_kernel<<<dim3(2, 112, 8), 256, 0, stream>>>(x, (bf16_t*)sub0p, ll0, 112, 112, 114, 114);
  conv_kernel<<<392, 512, 0, stream>>>(sub0p, wt, y0, 112, 112, 114, 114, 7, 49, 392);
  // level 1: 56x56, padded 66x66, tiles 4x4 of 16 (cover 64, writes guarded)
  border_kernel<<<137, 256, 0, stream>>>(sub1p, 56, 56, 66, 66);
  dwt_kernel<<<dim3(1, 56, 8), 256, 0, stream>>>(ll0, (bf16_t*)sub1p, ll1, 56, 56, 66, 66);
  conv_kernel<<<128, 512, 0, stream>>>(sub1p, wt, y1, 56, 56, 66, 66, 4, 16, 128);
  // level 2: 28x28, padded 34x34, tiles 2x2 of 16 (cover 32, writes guarded)
  border_kernel<<<37, 256, 0, stream>>>(sub2p, 28, 28, 34, 34);
  dwt_kernel<<<dim3(1, 28, 8), 256, 0, stream>>>(ll1, (bf16_t*)sub2p, nullptr, 28, 28, 34, 34);
  conv_kernel<<<32, 512, 0, stream>>>(sub2p, wt, y2, 28, 28, 34, 34, 2, 4, 32);
  // inverse chain (nll2/nll1 are the UPSAMPLED outputs: 56x56 and 112x112)
  idwt_kernel<<<dim3(1, 28, 8), 256, 0, stream>>>(y2, nullptr, nullptr, nll2, 28, 28);
  idwt_kernel<<<dim3(2, 56, 8), 256, 0, stream>>>(y1, nll2, nullptr, nll1, 56, 56);
  idwt_kernel<<<dim3(4, 112, 8), 256, 0, stream>>>(y0, nll1, bias, out, 112, 112);
}